// Round 7
// baseline (243.967 us; speedup 1.0000x reference)
//
#include <hip/hip_runtime.h>

// Problem constants (fixed by the reference)
#define E_DIM 1024
#define NH    16
#define HDIM  64
#define BB    2
#define LSEQ  2048
#define MTOT  (BB*LSEQ)   // 4096 tokens

typedef float  f32x4  __attribute__((ext_vector_type(4)));
typedef __bf16 bf16x8 __attribute__((ext_vector_type(8)));
typedef unsigned int   u32x4 __attribute__((ext_vector_type(4)));
typedef unsigned short u16x4 __attribute__((ext_vector_type(4)));
typedef unsigned short u16x8 __attribute__((ext_vector_type(8)));

union U16 {           // 16-byte fragment: 8 bf16
    u32x4  u4;
    bf16x8 b;
};

__device__ inline unsigned short f2bf(float f) {
    union { __bf16 h; unsigned short u; } x;
    x.h = (__bf16)f;
    return x.u;
}

__device__ __forceinline__ float fexp2(float x) {
#if __has_builtin(__builtin_amdgcn_exp2f)
    return __builtin_amdgcn_exp2f(x);   // single v_exp_f32
#else
    return exp2f(x);
#endif
}

// async global->LDS, 16B per lane. LDS dest is wave-uniform base + lane*16.
__device__ __forceinline__ void gload_lds16(const unsigned short* g, unsigned short* l) {
    __builtin_amdgcn_global_load_lds(
        (const __attribute__((address_space(1))) void*)g,
        (__attribute__((address_space(3))) void*)l, 16, 0, 0);
}

// ---------------- setup: fp32->bf16 converts (3 tensors) + W transposes (4) ----------------
// blocks [0,1536): convert (512/tensor); [1536,2560): transpose_w (256/weight).
__global__ __launch_bounds__(256) void setup(
    const float* __restrict__ q, const float* __restrict__ k, const float* __restrict__ v,
    unsigned short* __restrict__ Xq, unsigned short* __restrict__ Xk,
    unsigned short* __restrict__ Xv,
    const float* __restrict__ Wq, const float* __restrict__ Wk,
    const float* __restrict__ Wv, const float* __restrict__ Wo,
    unsigned short* __restrict__ Wqt, unsigned short* __restrict__ Wkt,
    unsigned short* __restrict__ Wvt, unsigned short* __restrict__ Wot)
{
    __shared__ unsigned short tile[64][80];
    int bx = blockIdx.x;
    int t = threadIdx.x;
    if (bx < 1536) {
        int z = bx >> 9;             // 0..2
        int blk = bx & 511;
        const float* in = z == 0 ? q : (z == 1 ? k : v);
        unsigned short* out = z == 0 ? Xq : (z == 1 ? Xk : Xv);
        const int n = MTOT * E_DIM;
        int i = (blk * 256 + t) * 4;
        const int stride = 512 * 256 * 4;
        for (; i < n; i += stride) {
            f32x4 val = *(const f32x4*)(in + i);
            u16x4 o = { f2bf(val.x), f2bf(val.y), f2bf(val.z), f2bf(val.w) };
            *(u16x4*)(out + i) = o;
        }
    } else {
        int r = bx - 1536;
        int z = r >> 8;              // 0..3
        int g = r & 255;
        const float* W = z == 0 ? Wq : (z == 1 ? Wk : (z == 2 ? Wv : Wo));
        unsigned short* Wt = z == 0 ? Wqt : (z == 1 ? Wkt : (z == 2 ? Wvt : Wot));
        int n0 = (g & 15) * 64, k0 = (g >> 4) * 64;
#pragma unroll
        for (int i = 0; i < 4; i++) {
            int idx = i * 256 + t;
            int kr = idx >> 4, nc = (idx & 15) * 4;
            f32x4 val = *(const f32x4*)(W + (size_t)(k0 + kr) * E_DIM + n0 + nc);
            u16x4 o = { f2bf(val.x), f2bf(val.y), f2bf(val.z), f2bf(val.w) };
            *(u16x4*)&tile[kr][nc] = o;
        }
        __syncthreads();
#pragma unroll
        for (int i = 0; i < 2; i++) {
            int idx = i * 256 + t;
            int nr = idx >> 3, kc = (idx & 7) * 8;
            union { unsigned short s[8]; u16x8 v; } pack;
#pragma unroll
            for (int j = 0; j < 8; j++) pack.s[j] = tile[kc + j][nr];
            *(u16x8*)(Wt + (size_t)(n0 + nr) * E_DIM + k0 + kc) = pack.v;
        }
    }
}

// ---------------- batched QKV projection GEMM (z = 0,1,2) ----------------
// All outputs head-major [bh][L][64] bf16 (V transposed by separate kernel —
// fusing V^T into this epilogue measured +10us twice, R5/R6; mechanism unknown).
__global__ __launch_bounds__(256) void gemm_qkv(
    const unsigned short* __restrict__ Xq, const unsigned short* __restrict__ Xk,
    const unsigned short* __restrict__ Xv,
    const unsigned short* __restrict__ Wqt, const unsigned short* __restrict__ Wkt,
    const unsigned short* __restrict__ Wvt,
    const float* __restrict__ bqp, const float* __restrict__ bkp, const float* __restrict__ bvp,
    unsigned short* __restrict__ Qh, unsigned short* __restrict__ Kh,
    unsigned short* __restrict__ Vh, float scaleQ)
{
    int z = blockIdx.z;
    const unsigned short* A  = z == 0 ? Xq  : (z == 1 ? Xk  : Xv);
    const unsigned short* Bt = z == 0 ? Wqt : (z == 1 ? Wkt : Wvt);
    const float* bias        = z == 0 ? bqp : (z == 1 ? bkp : bvp);
    unsigned short* out      = z == 0 ? Qh  : (z == 1 ? Kh  : Vh);
    float scale              = z == 0 ? scaleQ : 1.0f;

    __shared__ unsigned short Al[128 * 64];
    __shared__ unsigned short Bl[128 * 64];
    int t = threadIdx.x;
    int lane = t & 63, w = t >> 6;
    int qc = lane & 15, kg = lane >> 4;
    int m0 = blockIdx.x * 128, n0 = blockIdx.y * 128;
    int wr = (w >> 1) * 64, wc = (w & 1) * 64;

    int srow = w * 32 + (lane >> 3);
    int scol = (lane & 7) * 8;
    const unsigned short* Ag = A + (size_t)(m0 + srow) * E_DIM + scol;
    const unsigned short* Bg = Bt + (size_t)(n0 + srow) * E_DIM + scol;
    unsigned short* Asl = &Al[(w * 32) * 64];
    unsigned short* Bsl = &Bl[(w * 32) * 64];

    f32x4 acc[4][4];
#pragma unroll
    for (int i = 0; i < 4; i++)
#pragma unroll
        for (int j = 0; j < 4; j++)
            acc[i][j] = {0.f, 0.f, 0.f, 0.f};

    for (int kt = 0; kt < E_DIM / 64; kt++) {
        const unsigned short* Ak = Ag + (kt << 6);
        const unsigned short* Bk = Bg + (kt << 6);
        __syncthreads();
#pragma unroll
        for (int i = 0; i < 4; i++) {
            gload_lds16(Ak + (size_t)i * 8 * E_DIM, Asl + i * 8 * 64);
            gload_lds16(Bk + (size_t)i * 8 * E_DIM, Bsl + i * 8 * 64);
        }
        __syncthreads();
#pragma unroll
        for (int k2 = 0; k2 < 2; k2++) {
            U16 af[4], bg[4];
#pragma unroll
            for (int mi = 0; mi < 4; mi++)
                af[mi].u4 = *(const u32x4*)&Al[(wr + mi * 16 + qc) * 64 + k2 * 32 + kg * 8];
#pragma unroll
            for (int ni = 0; ni < 4; ni++)
                bg[ni].u4 = *(const u32x4*)&Bl[(wc + ni * 16 + qc) * 64 + k2 * 32 + kg * 8];
#pragma unroll
            for (int mi = 0; mi < 4; mi++)
#pragma unroll
                for (int ni = 0; ni < 4; ni++)
                    acc[mi][ni] = __builtin_amdgcn_mfma_f32_16x16x32_bf16(
                        af[mi].b, bg[ni].b, acc[mi][ni], 0, 0, 0);
        }
    }
    // Epilogue. D layout: col n = lane&15, row m = (lane>>4)*4 + r  [m89]
#pragma unroll
    for (int ni = 0; ni < 4; ni++) {
        int n = n0 + wc + ni * 16 + qc;
        float bval = bias[n];
        int h = n >> 6, hd = n & 63;
#pragma unroll
        for (int mi = 0; mi < 4; mi++) {
#pragma unroll
            for (int r = 0; r < 4; r++) {
                int m = m0 + wr + mi * 16 + kg * 4 + r;
                float v = (acc[mi][ni][r] + bval) * scale;
                int b = m >> 11, l = m & (LSEQ - 1);
                out[(((size_t)(b * NH + h)) * LSEQ + l) * HDIM + hd] = f2bf(v);
            }
        }
    }
}

// ---------------- V [bh][L][64] -> Vt [bh][64][L] (bf16) ----------------
__global__ __launch_bounds__(256) void transpose_v(
    const unsigned short* __restrict__ V, unsigned short* __restrict__ Vt)
{
    __shared__ unsigned short tile[64][80];
    int l0 = blockIdx.x * 64;
    int bh = blockIdx.y;
    const unsigned short* Vb = V + (size_t)bh * LSEQ * HDIM;
    unsigned short* Vtb = Vt + (size_t)bh * HDIM * LSEQ;
    int t = threadIdx.x;
#pragma unroll
    for (int i = 0; i < 2; i++) {
        int idx = i * 256 + t;
        int lr = idx >> 3, dc = (idx & 7) * 8;
        *(u16x8*)&tile[lr][dc] = *(const u16x8*)(Vb + (size_t)(l0 + lr) * HDIM + dc);
    }
    __syncthreads();
#pragma unroll
    for (int i = 0; i < 2; i++) {
        int idx = i * 256 + t;
        int dr = idx >> 3, lc = (idx & 7) * 8;
        union { unsigned short s[8]; u16x8 v; } pack;
#pragma unroll
        for (int j = 0; j < 8; j++) pack.s[j] = tile[lc + j][dr];
        *(u16x8*)(Vtb + (size_t)dr * LSEQ + l0 + lc) = pack.v;
    }
}

// ---------------- O-projection GEMM: 128x64 tile ----------------
__global__ __launch_bounds__(256) void gemm_o(
    const unsigned short* __restrict__ A, const unsigned short* __restrict__ Bt,
    const float* __restrict__ bias, float* __restrict__ outF)
{
    __shared__ unsigned short Al[128 * 64];
    __shared__ unsigned short Bl[64 * 64];
    int t = threadIdx.x;
    int lane = t & 63, w = t >> 6;
    int qc = lane & 15, kg = lane >> 4;
    int m0 = blockIdx.x * 128, n0 = blockIdx.y * 64;
    int wr = (w >> 1) * 64, wc = (w & 1) * 32;

    int srA = w * 32 + (lane >> 3);
    int srB = w * 16 + (lane >> 3);
    int scol = (lane & 7) * 8;
    const unsigned short* Ag = A + (size_t)(m0 + srA) * E_DIM + scol;
    const unsigned short* Bg = Bt + (size_t)(n0 + srB) * E_DIM + scol;
    unsigned short* Asl = &Al[(w * 32) * 64];
    unsigned short* Bsl = &Bl[(w * 16) * 64];

    f32x4 acc[4][2];
#pragma unroll
    for (int i = 0; i < 4; i++)
#pragma unroll
        for (int j = 0; j < 2; j++)
            acc[i][j] = {0.f, 0.f, 0.f, 0.f};

    for (int kt = 0; kt < E_DIM / 64; kt++) {
        const unsigned short* Ak = Ag + (kt << 6);
        const unsigned short* Bk = Bg + (kt << 6);
        __syncthreads();
#pragma unroll
        for (int i = 0; i < 4; i++)
            gload_lds16(Ak + (size_t)i * 8 * E_DIM, Asl + i * 8 * 64);
#pragma unroll
        for (int i = 0; i < 2; i++)
            gload_lds16(Bk + (size_t)i * 8 * E_DIM, Bsl + i * 8 * 64);
        __syncthreads();
#pragma unroll
        for (int k2 = 0; k2 < 2; k2++) {
            U16 af[4], bg[2];
#pragma unroll
            for (int mi = 0; mi < 4; mi++)
                af[mi].u4 = *(const u32x4*)&Al[(wr + mi * 16 + qc) * 64 + k2 * 32 + kg * 8];
#pragma unroll
            for (int ni = 0; ni < 2; ni++)
                bg[ni].u4 = *(const u32x4*)&Bl[(wc + ni * 16 + qc) * 64 + k2 * 32 + kg * 8];
#pragma unroll
            for (int mi = 0; mi < 4; mi++)
#pragma unroll
                for (int ni = 0; ni < 2; ni++)
                    acc[mi][ni] = __builtin_amdgcn_mfma_f32_16x16x32_bf16(
                        af[mi].b, bg[ni].b, acc[mi][ni], 0, 0, 0);
        }
    }
#pragma unroll
    for (int ni = 0; ni < 2; ni++) {
        int n = n0 + wc + ni * 16 + qc;
        float bval = bias[n];
#pragma unroll
        for (int mi = 0; mi < 4; mi++) {
#pragma unroll
            for (int r = 0; r < 4; r++) {
                int m = m0 + wr + mi * 16 + kg * 4 + r;
                outF[(size_t)m * E_DIM + n] = acc[mi][ni][r] + bval;
            }
        }
    }
}

// ---------------- causal flash attention: 128-row blocks, grid 512 ----------------
// Qh/Kh: [bh][L][64] bf16 (Q pre-scaled by log2e/8). Vt: [bh][64][L] bf16.
// Grid 512 linear, 512 threads (8 waves). Block owns (bh, qb) — one 128-row
// q-block; wave w gets 16 rows. Same per-q-block staging volume as the paired
// R4 version (R5 lesson: don't shrink q-rows), but 2 blocks/CU instead of 1.
// Heavy qb dispatched first within each XCD's 64-block stream for backfill.
// K/V kv-tiles staged once per block via global_load_lds into double-buffered
// swizzled LDS. Swapped-operand MFMA; per-lane softmax; T5 setprio on MFMA.
__global__ __launch_bounds__(512, 2) void attn_causal(
    const unsigned short* __restrict__ Qh, const unsigned short* __restrict__ Kh,
    const unsigned short* __restrict__ Vt, unsigned short* __restrict__ Ctx)
{
    __shared__ unsigned short Kst[2][64 * 64];   // [kv][d], swizzled, 8KB/buf
    __shared__ unsigned short Vst[2][64 * 64];   // [d][kv], swizzled, 8KB/buf
    __shared__ unsigned short Pl[8][16 * 72];    // per-wave P[q][kv], stride 72

    // XCD chunking: XCD x gets flat in [64x, 64x+64) -> bh in [4x, 4x+4).
    int flat_hw = blockIdx.x;
    int flat = (flat_hw & 7) * 64 + (flat_hw >> 3);
    int bh = flat >> 4;            // 0..31
    int qb = 15 - (flat & 15);     // heavy q-blocks dispatched first

    int t = threadIdx.x;
    int w = t >> 6, lane = t & 63;
    int qc = lane & 15, kg = lane >> 4;

    const unsigned short* Qb  = Qh + (size_t)bh * LSEQ * HDIM;
    const unsigned short* Kb  = Kh + (size_t)bh * LSEQ * HDIM;
    const unsigned short* Vbt = Vt + (size_t)bh * HDIM * LSEQ;
    int b = bh >> 4, h = bh & 15;
    unsigned short* Cb = Ctx + ((size_t)b * LSEQ) * E_DIM + h * HDIM;

    // staging lane constants: lane stages 16B of row (8w+lrow), swizzled col
    int lrow = lane >> 3;                      // 0..7
    int c16s = ((lane & 7) ^ lrow) * 8;        // pre-swizzled source col (elems)
    int krow = 8 * w + lrow;                   // tile-local row this lane stages
    unsigned short* KstW0 = &Kst[0][w * 512];  // wave-uniform LDS bases
    unsigned short* KstW1 = &Kst[1][w * 512];
    unsigned short* VstW0 = &Vst[0][w * 512];
    unsigned short* VstW1 = &Vst[1][w * 512];

    unsigned short* Pw = &Pl[w][0];
    unsigned short* Pst = Pw + qc * 72 + kg * 4;        // store: row q=qc, col f*16+kg*4
    const unsigned short* Pld = Pw + qc * 72 + kg * 8;  // load B-frag: col q=qc, k=kv

    int sw = (qc & 7) * 8;   // read-side swizzle term for row qc within 16-row frags

    int q0w = qb * 128 + w * 16;          // this wave's first q row
    int nt = 2 * qb + 2;                  // kv tiles for the block (uniform)
    int nta = (q0w + 79) >> 6;            // active tiles for this wave

    // Q B-frags (col=q=lane&15, k=d=kg*8+j)
    U16 qf0, qf1;
    qf0.u4 = *(const u32x4*)(Qb + (size_t)(q0w + qc) * HDIM + kg * 8);
    qf1.u4 = *(const u32x4*)(Qb + (size_t)(q0w + qc) * HDIM + 32 + kg * 8);

    f32x4 ctx[4];
#pragma unroll
    for (int df = 0; df < 4; df++) ctx[df] = {0.f, 0.f, 0.f, 0.f};
    float mrun = -1e30f, lrun = 0.f;

    // prologue: stage tile 0 into buffer 0
    gload_lds16(Kb + (size_t)krow * HDIM + c16s, KstW0);
    gload_lds16(Vbt + (size_t)krow * LSEQ + c16s, VstW0);
    __syncthreads();   // drains vmcnt: tile 0 visible

    for (int tt = 0; tt < nt; tt++) {
        int kv0 = tt << 6;
        int cur = tt & 1;
        // stage next tile into the other buffer (async; drains at barrier)
        if (tt + 1 < nt) {
            int kvn = kv0 + 64;
            gload_lds16(Kb + (size_t)(kvn + krow) * HDIM + c16s,
                        cur ? KstW0 : KstW1);
            gload_lds16(Vbt + (size_t)krow * LSEQ + kvn + c16s,
                        cur ? VstW0 : VstW1);
        }
        if (tt < nta) {
            const unsigned short* Kc = &Kst[cur][0];
            const unsigned short* Vc = &Vst[cur][0];
            // ---- S^T = K Q^T : rows kv = f*16+kg*4+r, col q = qc ----
            f32x4 s[4];
            __builtin_amdgcn_s_setprio(1);
#pragma unroll
            for (int f = 0; f < 4; f++) {
                U16 k0_, k1_;   // A-frag row kv=f*16+qc, k=d (2 halves)
                k0_.u4 = *(const u32x4*)&Kc[(f * 16 + qc) * 64 + ((kg * 8) ^ sw)];
                k1_.u4 = *(const u32x4*)&Kc[(f * 16 + qc) * 64 + ((32 + kg * 8) ^ sw)];
                f32x4 z = {0.f, 0.f, 0.f, 0.f};
                z = __builtin_amdgcn_mfma_f32_16x16x32_bf16(k0_.b, qf0.b, z, 0, 0, 0);
                z = __builtin_amdgcn_mfma_f32_16x16x32_bf16(k1_.b, qf1.b, z, 0, 0, 0);
                s[f] = z;
            }
            __builtin_amdgcn_s_setprio(0);
            // ---- causal mask (diagonal tiles only) ----
            if (kv0 + 63 > q0w) {
                int qi = q0w + qc;
#pragma unroll
                for (int f = 0; f < 4; f++) {
#pragma unroll
                    for (int r = 0; r < 4; r++) {
                        if (kv0 + f * 16 + kg * 4 + r > qi) s[f][r] = -1e30f;
                    }
                }
            }
            // ---- per-lane softmax (16 regs) + 2 cross-lane steps ----
            float m0_ = fmaxf(fmaxf(s[0][0], s[0][1]), fmaxf(s[0][2], s[0][3]));
            float m1_ = fmaxf(fmaxf(s[1][0], s[1][1]), fmaxf(s[1][2], s[1][3]));
            float m2_ = fmaxf(fmaxf(s[2][0], s[2][1]), fmaxf(s[2][2], s[2][3]));
            float m3_ = fmaxf(fmaxf(s[3][0], s[3][1]), fmaxf(s[3][2], s[3][3]));
            float tm = fmaxf(fmaxf(m0_, m1_), fmaxf(m2_, m3_));
            tm = fmaxf(tm, __shfl_xor(tm, 16));
            tm = fmaxf(tm, __shfl_xor(tm, 32));
            float mn;
            if (__all(tm - mrun <= 8.0f)) {       // T13 defer-max
                mn = mrun;
            } else {
                mn = fmaxf(mrun, tm);
                float sc = fexp2(mrun - mn);
                mrun = mn;
                lrun *= sc;
#pragma unroll
                for (int df = 0; df < 4; df++) ctx[df] *= sc;
            }
#pragma unroll
            for (int f = 0; f < 4; f++)
#pragma unroll
                for (int r = 0; r < 4; r++)
                    s[f][r] = fexp2(s[f][r] - mn);
            float rs = ((s[0][0] + s[0][1]) + (s[0][2] + s[0][3]))
                     + ((s[1][0] + s[1][1]) + (s[1][2] + s[1][3]))
                     + ((s[2][0] + s[2][1]) + (s[2][2] + s[2][3]))
                     + ((s[3][0] + s[3][1]) + (s[3][2] + s[3][3]));
            rs += __shfl_xor(rs, 16);
            rs += __shfl_xor(rs, 32);
            lrun += rs;
            // ---- store P[q=qc][kv] ----
#pragma unroll
            for (int f = 0; f < 4; f++) {
                u16x4 p = { f2bf(s[f][0]), f2bf(s[f][1]), f2bf(s[f][2]), f2bf(s[f][3]) };
                *(u16x4*)(Pst + f * 16) = p;
            }
            // ---- ctx^T += V^T P^T ----
            __builtin_amdgcn_s_setprio(1);
#pragma unroll
            for (int k2 = 0; k2 < 2; k2++) {
                U16 ap;
                ap.u4 = *(const u32x4*)(Pld + k2 * 32);
#pragma unroll
                for (int df = 0; df < 4; df++) {
                    U16 vf;   // A-frag row d=df*16+qc, k=kv (half k2)
                    vf.u4 = *(const u32x4*)&Vc[(df * 16 + qc) * 64 +
                                               ((k2 * 32 + kg * 8) ^ sw)];
                    ctx[df] = __builtin_amdgcn_mfma_f32_16x16x32_bf16(
                        vf.b, ap.b, ctx[df], 0, 0, 0);
                }
            }
            __builtin_amdgcn_s_setprio(0);
        }
        __syncthreads();   // drains staging vmcnt + separates buffers
    }
    // ---- normalize + store: lane holds q = q0w+qc, d = df*16+kg*4+r ----
    float inv = 1.f / lrun;
    unsigned short* Cq = Cb + (size_t)(q0w + qc) * E_DIM;
#pragma unroll
    for (int df = 0; df < 4; df++) {
        u16x4 o = { f2bf(ctx[df][0] * inv), f2bf(ctx[df][1] * inv),
                    f2bf(ctx[df][2] * inv), f2bf(ctx[df][3] * inv) };
        *(u16x4*)(Cq + df * 16 + kg * 4) = o;
    }
}

// ---------------- launcher ----------------
extern "C" void kernel_launch(void* const* d_in, const int* in_sizes, int n_in,
                              void* d_out, int out_size, void* d_ws, size_t ws_size,
                              hipStream_t stream)
{
    (void)in_sizes; (void)n_in; (void)out_size; (void)ws_size;
    const float* query = (const float*)d_in[0];
    const float* key_  = (const float*)d_in[1];
    const float* value = (const float*)d_in[2];
    const float* Wq = (const float*)d_in[5];
    const float* bq = (const float*)d_in[6];
    const float* Wk = (const float*)d_in[7];
    const float* bk = (const float*)d_in[8];
    const float* Wv = (const float*)d_in[9];
    const float* bv = (const float*)d_in[10];
    const float* Wo = (const float*)d_in[11];
    const float* bo = (const float*)d_in[12];
    float* out = (float*)d_out;

    char* ws = (char*)d_ws;
    const size_t MB = 1024 * 1024;
    unsigned short* Xq  = (unsigned short*)(ws + 0 * MB);
    unsigned short* Xk  = (unsigned short*)(ws + 8 * MB);
    unsigned short* Xv  = (unsigned short*)(ws + 16 * MB);
    unsigned short* Wqt = (unsigned short*)(ws + 24 * MB);
    unsigned short* Wkt = (unsigned short*)(ws + 26 * MB);
    unsigned short* Wvt = (unsigned short*)(ws + 28 * MB);
    unsigned short* Wot = (unsigned short*)(ws + 30 * MB);
    unsigned short* Qh  = (unsigned short*)(ws + 32 * MB);
    unsigned short* Kh  = (unsigned short*)(ws + 40 * MB);
    unsigned short* Vh  = (unsigned short*)(ws + 48 * MB);
    unsigned short* Vtp = (unsigned short*)(ws + 56 * MB);
    unsigned short* Ctx = (unsigned short*)(ws + 0 * MB);  // reuse Xq

    setup<<<dim3(2560), 256, 0, stream>>>(query, key_, value, Xq, Xk, Xv,
                                          Wq, Wk, Wv, Wo, Wqt, Wkt, Wvt, Wot);

    const float SCALE_Q = 0.18033688011112042f;  // log2(e) / sqrt(HD)=8
    gemm_qkv<<<dim3(32, 8, 3), 256, 0, stream>>>(Xq, Xk, Xv, Wqt, Wkt, Wvt,
                                                 bq, bk, bv, Qh, Kh, Vh, SCALE_Q);

    transpose_v<<<dim3(32, 32), 256, 0, stream>>>(Vh, Vtp);

    attn_causal<<<dim3(512), 512, 0, stream>>>(Qh, Kh, Vtp, Ctx);

    gemm_o<<<dim3(32, 16), 256, 0, stream>>>(Ctx, Wot, bo, out);
}

// Round 8
// 234.531 us; speedup vs baseline: 1.0402x; 1.0402x over previous
//
#include <hip/hip_runtime.h>

// Problem constants (fixed by the reference)
#define E_DIM 1024
#define NH    16
#define HDIM  64
#define BB    2
#define LSEQ  2048
#define MTOT  (BB*LSEQ)   // 4096 tokens

typedef float  f32x4  __attribute__((ext_vector_type(4)));
typedef __bf16 bf16x8 __attribute__((ext_vector_type(8)));
typedef unsigned int   u32x4 __attribute__((ext_vector_type(4)));
typedef unsigned short u16x4 __attribute__((ext_vector_type(4)));
typedef unsigned short u16x8 __attribute__((ext_vector_type(8)));

union U16 {           // 16-byte fragment: 8 bf16
    u32x4  u4;
    bf16x8 b;
};

__device__ inline unsigned short f2bf(float f) {
    union { __bf16 h; unsigned short u; } x;
    x.h = (__bf16)f;
    return x.u;
}

__device__ __forceinline__ float fexp2(float x) {
#if __has_builtin(__builtin_amdgcn_exp2f)
    return __builtin_amdgcn_exp2f(x);   // single v_exp_f32
#else
    return exp2f(x);
#endif
}

// async global->LDS, 16B per lane. LDS dest is wave-uniform base + lane*16.
__device__ __forceinline__ void gload_lds16(const unsigned short* g, unsigned short* l) {
    __builtin_amdgcn_global_load_lds(
        (const __attribute__((address_space(1))) void*)g,
        (__attribute__((address_space(3))) void*)l, 16, 0, 0);
}

// ---------------- setup: fp32->bf16 converts (3 tensors) + W transposes (4) ----------------
__global__ __launch_bounds__(256) void setup(
    const float* __restrict__ q, const float* __restrict__ k, const float* __restrict__ v,
    unsigned short* __restrict__ Xq, unsigned short* __restrict__ Xk,
    unsigned short* __restrict__ Xv,
    const float* __restrict__ Wq, const float* __restrict__ Wk,
    const float* __restrict__ Wv, const float* __restrict__ Wo,
    unsigned short* __restrict__ Wqt, unsigned short* __restrict__ Wkt,
    unsigned short* __restrict__ Wvt, unsigned short* __restrict__ Wot)
{
    __shared__ unsigned short tile[64][80];
    int bx = blockIdx.x;
    int t = threadIdx.x;
    if (bx < 1536) {
        int z = bx >> 9;             // 0..2
        int blk = bx & 511;
        const float* in = z == 0 ? q : (z == 1 ? k : v);
        unsigned short* out = z == 0 ? Xq : (z == 1 ? Xk : Xv);
        const int n = MTOT * E_DIM;
        int i = (blk * 256 + t) * 4;
        const int stride = 512 * 256 * 4;
        for (; i < n; i += stride) {
            f32x4 val = *(const f32x4*)(in + i);
            u16x4 o = { f2bf(val.x), f2bf(val.y), f2bf(val.z), f2bf(val.w) };
            *(u16x4*)(out + i) = o;
        }
    } else {
        int r = bx - 1536;
        int z = r >> 8;              // 0..3
        int g = r & 255;
        const float* W = z == 0 ? Wq : (z == 1 ? Wk : (z == 2 ? Wv : Wo));
        unsigned short* Wt = z == 0 ? Wqt : (z == 1 ? Wkt : (z == 2 ? Wvt : Wot));
        int n0 = (g & 15) * 64, k0 = (g >> 4) * 64;
#pragma unroll
        for (int i = 0; i < 4; i++) {
            int idx = i * 256 + t;
            int kr = idx >> 4, nc = (idx & 15) * 4;
            f32x4 val = *(const f32x4*)(W + (size_t)(k0 + kr) * E_DIM + n0 + nc);
            u16x4 o = { f2bf(val.x), f2bf(val.y), f2bf(val.z), f2bf(val.w) };
            *(u16x4*)&tile[kr][nc] = o;
        }
        __syncthreads();
#pragma unroll
        for (int i = 0; i < 2; i++) {
            int idx = i * 256 + t;
            int nr = idx >> 3, kc = (idx & 7) * 8;
            union { unsigned short s[8]; u16x8 v; } pack;
#pragma unroll
            for (int j = 0; j < 8; j++) pack.s[j] = tile[kc + j][nr];
            *(u16x8*)(Wt + (size_t)(n0 + nr) * E_DIM + k0 + kc) = pack.v;
        }
    }
}

// ---------------- batched QKV projection GEMM (z = 0,1,2) ----------------
// All outputs head-major [bh][L][64] bf16 (V transposed by separate kernel —
// fusing V^T into this epilogue measured +10us twice, R5/R6).
__global__ __launch_bounds__(256) void gemm_qkv(
    const unsigned short* __restrict__ Xq, const unsigned short* __restrict__ Xk,
    const unsigned short* __restrict__ Xv,
    const unsigned short* __restrict__ Wqt, const unsigned short* __restrict__ Wkt,
    const unsigned short* __restrict__ Wvt,
    const float* __restrict__ bqp, const float* __restrict__ bkp, const float* __restrict__ bvp,
    unsigned short* __restrict__ Qh, unsigned short* __restrict__ Kh,
    unsigned short* __restrict__ Vh, float scaleQ)
{
    int z = blockIdx.z;
    const unsigned short* A  = z == 0 ? Xq  : (z == 1 ? Xk  : Xv);
    const unsigned short* Bt = z == 0 ? Wqt : (z == 1 ? Wkt : Wvt);
    const float* bias        = z == 0 ? bqp : (z == 1 ? bkp : bvp);
    unsigned short* out      = z == 0 ? Qh  : (z == 1 ? Kh  : Vh);
    float scale              = z == 0 ? scaleQ : 1.0f;

    __shared__ unsigned short Al[128 * 64];
    __shared__ unsigned short Bl[128 * 64];
    int t = threadIdx.x;
    int lane = t & 63, w = t >> 6;
    int qc = lane & 15, kg = lane >> 4;
    int m0 = blockIdx.x * 128, n0 = blockIdx.y * 128;
    int wr = (w >> 1) * 64, wc = (w & 1) * 64;

    int srow = w * 32 + (lane >> 3);
    int scol = (lane & 7) * 8;
    const unsigned short* Ag = A + (size_t)(m0 + srow) * E_DIM + scol;
    const unsigned short* Bg = Bt + (size_t)(n0 + srow) * E_DIM + scol;
    unsigned short* Asl = &Al[(w * 32) * 64];
    unsigned short* Bsl = &Bl[(w * 32) * 64];

    f32x4 acc[4][4];
#pragma unroll
    for (int i = 0; i < 4; i++)
#pragma unroll
        for (int j = 0; j < 4; j++)
            acc[i][j] = {0.f, 0.f, 0.f, 0.f};

    for (int kt = 0; kt < E_DIM / 64; kt++) {
        const unsigned short* Ak = Ag + (kt << 6);
        const unsigned short* Bk = Bg + (kt << 6);
        __syncthreads();
#pragma unroll
        for (int i = 0; i < 4; i++) {
            gload_lds16(Ak + (size_t)i * 8 * E_DIM, Asl + i * 8 * 64);
            gload_lds16(Bk + (size_t)i * 8 * E_DIM, Bsl + i * 8 * 64);
        }
        __syncthreads();
#pragma unroll
        for (int k2 = 0; k2 < 2; k2++) {
            U16 af[4], bg[4];
#pragma unroll
            for (int mi = 0; mi < 4; mi++)
                af[mi].u4 = *(const u32x4*)&Al[(wr + mi * 16 + qc) * 64 + k2 * 32 + kg * 8];
#pragma unroll
            for (int ni = 0; ni < 4; ni++)
                bg[ni].u4 = *(const u32x4*)&Bl[(wc + ni * 16 + qc) * 64 + k2 * 32 + kg * 8];
#pragma unroll
            for (int mi = 0; mi < 4; mi++)
#pragma unroll
                for (int ni = 0; ni < 4; ni++)
                    acc[mi][ni] = __builtin_amdgcn_mfma_f32_16x16x32_bf16(
                        af[mi].b, bg[ni].b, acc[mi][ni], 0, 0, 0);
        }
    }
#pragma unroll
    for (int ni = 0; ni < 4; ni++) {
        int n = n0 + wc + ni * 16 + qc;
        float bval = bias[n];
        int h = n >> 6, hd = n & 63;
#pragma unroll
        for (int mi = 0; mi < 4; mi++) {
#pragma unroll
            for (int r = 0; r < 4; r++) {
                int m = m0 + wr + mi * 16 + kg * 4 + r;
                float v = (acc[mi][ni][r] + bval) * scale;
                int b = m >> 11, l = m & (LSEQ - 1);
                out[(((size_t)(b * NH + h)) * LSEQ + l) * HDIM + hd] = f2bf(v);
            }
        }
    }
}

// ---------------- V [bh][L][64] -> Vt [bh][64][L] (bf16) ----------------
__global__ __launch_bounds__(256) void transpose_v(
    const unsigned short* __restrict__ V, unsigned short* __restrict__ Vt)
{
    __shared__ unsigned short tile[64][80];
    int l0 = blockIdx.x * 64;
    int bh = blockIdx.y;
    const unsigned short* Vb = V + (size_t)bh * LSEQ * HDIM;
    unsigned short* Vtb = Vt + (size_t)bh * HDIM * LSEQ;
    int t = threadIdx.x;
#pragma unroll
    for (int i = 0; i < 2; i++) {
        int idx = i * 256 + t;
        int lr = idx >> 3, dc = (idx & 7) * 8;
        *(u16x8*)&tile[lr][dc] = *(const u16x8*)(Vb + (size_t)(l0 + lr) * HDIM + dc);
    }
    __syncthreads();
#pragma unroll
    for (int i = 0; i < 2; i++) {
        int idx = i * 256 + t;
        int dr = idx >> 3, lc = (idx & 7) * 8;
        union { unsigned short s[8]; u16x8 v; } pack;
#pragma unroll
        for (int j = 0; j < 8; j++) pack.s[j] = tile[lc + j][dr];
        *(u16x8*)(Vtb + (size_t)dr * LSEQ + l0 + lc) = pack.v;
    }
}

// ---------------- O-projection GEMM: 128x64 tile ----------------
__global__ __launch_bounds__(256) void gemm_o(
    const unsigned short* __restrict__ A, const unsigned short* __restrict__ Bt,
    const float* __restrict__ bias, float* __restrict__ outF)
{
    __shared__ unsigned short Al[128 * 64];
    __shared__ unsigned short Bl[64 * 64];
    int t = threadIdx.x;
    int lane = t & 63, w = t >> 6;
    int qc = lane & 15, kg = lane >> 4;
    int m0 = blockIdx.x * 128, n0 = blockIdx.y * 64;
    int wr = (w >> 1) * 64, wc = (w & 1) * 32;

    int srA = w * 32 + (lane >> 3);
    int srB = w * 16 + (lane >> 3);
    int scol = (lane & 7) * 8;
    const unsigned short* Ag = A + (size_t)(m0 + srA) * E_DIM + scol;
    const unsigned short* Bg = Bt + (size_t)(n0 + srB) * E_DIM + scol;
    unsigned short* Asl = &Al[(w * 32) * 64];
    unsigned short* Bsl = &Bl[(w * 16) * 64];

    f32x4 acc[4][2];
#pragma unroll
    for (int i = 0; i < 4; i++)
#pragma unroll
        for (int j = 0; j < 2; j++)
            acc[i][j] = {0.f, 0.f, 0.f, 0.f};

    for (int kt = 0; kt < E_DIM / 64; kt++) {
        const unsigned short* Ak = Ag + (kt << 6);
        const unsigned short* Bk = Bg + (kt << 6);
        __syncthreads();
#pragma unroll
        for (int i = 0; i < 4; i++)
            gload_lds16(Ak + (size_t)i * 8 * E_DIM, Asl + i * 8 * 64);
#pragma unroll
        for (int i = 0; i < 2; i++)
            gload_lds16(Bk + (size_t)i * 8 * E_DIM, Bsl + i * 8 * 64);
        __syncthreads();
#pragma unroll
        for (int k2 = 0; k2 < 2; k2++) {
            U16 af[4], bg[2];
#pragma unroll
            for (int mi = 0; mi < 4; mi++)
                af[mi].u4 = *(const u32x4*)&Al[(wr + mi * 16 + qc) * 64 + k2 * 32 + kg * 8];
#pragma unroll
            for (int ni = 0; ni < 2; ni++)
                bg[ni].u4 = *(const u32x4*)&Bl[(wc + ni * 16 + qc) * 64 + k2 * 32 + kg * 8];
#pragma unroll
            for (int mi = 0; mi < 4; mi++)
#pragma unroll
                for (int ni = 0; ni < 2; ni++)
                    acc[mi][ni] = __builtin_amdgcn_mfma_f32_16x16x32_bf16(
                        af[mi].b, bg[ni].b, acc[mi][ni], 0, 0, 0);
        }
    }
#pragma unroll
    for (int ni = 0; ni < 2; ni++) {
        int n = n0 + wc + ni * 16 + qc;
        float bval = bias[n];
#pragma unroll
        for (int mi = 0; mi < 4; mi++) {
#pragma unroll
            for (int r = 0; r < 4; r++) {
                int m = m0 + wr + mi * 16 + kg * 4 + r;
                outF[(size_t)m * E_DIM + n] = acc[mi][ni][r] + bval;
            }
        }
    }
}

// ---- per-tile attention compute for one q-state (inlined; all statically unrolled) ----
__device__ __forceinline__ void attn_tile(
    const unsigned short* __restrict__ Kc, const unsigned short* __restrict__ Vc,
    unsigned short* __restrict__ Pst, const unsigned short* __restrict__ Pld,
    int sw, int kg, int qc, int kv0, int q0w,
    const U16& qf0, const U16& qf1,
    f32x4 ctx[4], float& mrun, float& lrun)
{
    // ---- S^T = K Q^T : rows kv = f*16+kg*4+r, col q = qc ----
    f32x4 s[4];
    __builtin_amdgcn_s_setprio(1);
#pragma unroll
    for (int f = 0; f < 4; f++) {
        U16 k0_, k1_;   // A-frag row kv=f*16+qc, k=d (2 halves)
        k0_.u4 = *(const u32x4*)&Kc[(f * 16 + qc) * 64 + ((kg * 8) ^ sw)];
        k1_.u4 = *(const u32x4*)&Kc[(f * 16 + qc) * 64 + ((32 + kg * 8) ^ sw)];
        f32x4 z = {0.f, 0.f, 0.f, 0.f};
        z = __builtin_amdgcn_mfma_f32_16x16x32_bf16(k0_.b, qf0.b, z, 0, 0, 0);
        z = __builtin_amdgcn_mfma_f32_16x16x32_bf16(k1_.b, qf1.b, z, 0, 0, 0);
        s[f] = z;
    }
    __builtin_amdgcn_s_setprio(0);
    // ---- causal mask (diagonal tiles only) ----
    if (kv0 + 63 > q0w) {
        int qi = q0w + qc;
#pragma unroll
        for (int f = 0; f < 4; f++) {
#pragma unroll
            for (int r = 0; r < 4; r++) {
                if (kv0 + f * 16 + kg * 4 + r > qi) s[f][r] = -1e30f;
            }
        }
    }
    // ---- per-lane softmax (16 regs) + 2 cross-lane steps ----
    float m0_ = fmaxf(fmaxf(s[0][0], s[0][1]), fmaxf(s[0][2], s[0][3]));
    float m1_ = fmaxf(fmaxf(s[1][0], s[1][1]), fmaxf(s[1][2], s[1][3]));
    float m2_ = fmaxf(fmaxf(s[2][0], s[2][1]), fmaxf(s[2][2], s[2][3]));
    float m3_ = fmaxf(fmaxf(s[3][0], s[3][1]), fmaxf(s[3][2], s[3][3]));
    float tm = fmaxf(fmaxf(m0_, m1_), fmaxf(m2_, m3_));
    tm = fmaxf(tm, __shfl_xor(tm, 16));
    tm = fmaxf(tm, __shfl_xor(tm, 32));
    float mn;
    if (__all(tm - mrun <= 8.0f)) {       // T13 defer-max
        mn = mrun;
    } else {
        mn = fmaxf(mrun, tm);
        float sc = fexp2(mrun - mn);
        mrun = mn;
        lrun *= sc;
#pragma unroll
        for (int df = 0; df < 4; df++) ctx[df] *= sc;
    }
#pragma unroll
    for (int f = 0; f < 4; f++)
#pragma unroll
        for (int r = 0; r < 4; r++)
            s[f][r] = fexp2(s[f][r] - mn);
    float rs = ((s[0][0] + s[0][1]) + (s[0][2] + s[0][3]))
             + ((s[1][0] + s[1][1]) + (s[1][2] + s[1][3]))
             + ((s[2][0] + s[2][1]) + (s[2][2] + s[2][3]))
             + ((s[3][0] + s[3][1]) + (s[3][2] + s[3][3]));
    rs += __shfl_xor(rs, 16);
    rs += __shfl_xor(rs, 32);
    lrun += rs;
    // ---- store P[q=qc][kv] ----
#pragma unroll
    for (int f = 0; f < 4; f++) {
        u16x4 p = { f2bf(s[f][0]), f2bf(s[f][1]), f2bf(s[f][2]), f2bf(s[f][3]) };
        *(u16x4*)(Pst + f * 16) = p;
    }
    // ---- ctx^T += V^T P^T ----
    __builtin_amdgcn_s_setprio(1);
#pragma unroll
    for (int k2 = 0; k2 < 2; k2++) {
        U16 ap;
        ap.u4 = *(const u32x4*)(Pld + k2 * 32);
#pragma unroll
        for (int df = 0; df < 4; df++) {
            U16 vf;   // A-frag row d=df*16+qc, k=kv (half k2)
            vf.u4 = *(const u32x4*)&Vc[(df * 16 + qc) * 64 +
                                       ((k2 * 32 + kg * 8) ^ sw)];
            ctx[df] = __builtin_amdgcn_mfma_f32_16x16x32_bf16(
                vf.b, ap.b, ctx[df], 0, 0, 0);
        }
    }
    __builtin_amdgcn_s_setprio(0);
}

// ---------------- causal flash attention: dual-q-tile blocks ----------------
// Qh/Kh: [bh][L][64] bf16 (Q pre-scaled by log2e/8). Vt: [bh][64][L] bf16.
// Grid 256 linear, 512 threads (8 waves). Block owns bh and processes q-blocks
// qbA = pr AND qbB = 15-pr SIMULTANEOUSLY against one staged K/V stream
// (B's kv range covers A's): per-bh staging 272 -> 200 tiles vs the 2-pass R4
// form, 2x compute per barrier interval, uniform ~34 compute-tiles per block.
// (R7 lesson: never trade balance for occupancy; R5 lesson: don't shrink
// q-rows per wave — this keeps 16 rows/wave and 1 block/CU.)
__global__ __launch_bounds__(512, 2) void attn_causal(
    const unsigned short* __restrict__ Qh, const unsigned short* __restrict__ Kh,
    const unsigned short* __restrict__ Vt, unsigned short* __restrict__ Ctx)
{
    __shared__ unsigned short Kst[2][64 * 64];   // [kv][d], swizzled, 8KB/buf
    __shared__ unsigned short Vst[2][64 * 64];   // [d][kv], swizzled, 8KB/buf
    __shared__ unsigned short Pl[8][16 * 72];    // per-wave P[q][kv], stride 72

    // XCD chunking: XCD x gets flat in [32x,32x+32) -> bh in [4x,4x+4): K/V fit L2
    int flat_hw = blockIdx.x;
    int flat = (flat_hw & 7) * 32 + (flat_hw >> 3);
    int bh = flat >> 3;          // 0..31
    int pr = flat & 7;           // qbA = pr, qbB = 15-pr

    int t = threadIdx.x;
    int w = t >> 6, lane = t & 63;
    int qc = lane & 15, kg = lane >> 4;

    const unsigned short* Qb  = Qh + (size_t)bh * LSEQ * HDIM;
    const unsigned short* Kb  = Kh + (size_t)bh * LSEQ * HDIM;
    const unsigned short* Vbt = Vt + (size_t)bh * HDIM * LSEQ;
    int b = bh >> 4, h = bh & 15;
    unsigned short* Cb = Ctx + ((size_t)b * LSEQ) * E_DIM + h * HDIM;

    // staging lane constants: lane stages 16B of row (8w+lrow), swizzled col
    int lrow = lane >> 3;                      // 0..7
    int c16s = ((lane & 7) ^ lrow) * 8;        // pre-swizzled source col (elems)
    int krow = 8 * w + lrow;                   // tile-local row this lane stages
    unsigned short* KstW0 = &Kst[0][w * 512];  // wave-uniform LDS bases
    unsigned short* KstW1 = &Kst[1][w * 512];
    unsigned short* VstW0 = &Vst[0][w * 512];
    unsigned short* VstW1 = &Vst[1][w * 512];

    unsigned short* Pw = &Pl[w][0];
    unsigned short* Pst = Pw + qc * 72 + kg * 4;        // store: row q=qc, col f*16+kg*4
    const unsigned short* Pld = Pw + qc * 72 + kg * 8;  // load B-frag: col q=qc, k=kv

    int sw = (qc & 7) * 8;   // read-side swizzle term

    int q0A = pr * 128 + w * 16;
    int q0B = (15 - pr) * 128 + w * 16;
    int nt   = 2 * (15 - pr) + 2;         // B is the heavier q-block (pr<=7)
    int ntaA = (q0A + 79) >> 6;           // active tiles for this wave, state A
    int ntaB = (q0B + 79) >> 6;

    // Q B-frags (col=q=lane&15, k=d=kg*8+j) for both states
    U16 qfA0, qfA1, qfB0, qfB1;
    qfA0.u4 = *(const u32x4*)(Qb + (size_t)(q0A + qc) * HDIM + kg * 8);
    qfA1.u4 = *(const u32x4*)(Qb + (size_t)(q0A + qc) * HDIM + 32 + kg * 8);
    qfB0.u4 = *(const u32x4*)(Qb + (size_t)(q0B + qc) * HDIM + kg * 8);
    qfB1.u4 = *(const u32x4*)(Qb + (size_t)(q0B + qc) * HDIM + 32 + kg * 8);

    f32x4 ctxA[4], ctxB[4];
#pragma unroll
    for (int df = 0; df < 4; df++) {
        ctxA[df] = {0.f, 0.f, 0.f, 0.f};
        ctxB[df] = {0.f, 0.f, 0.f, 0.f};
    }
    float mA = -1e30f, lA = 0.f, mB = -1e30f, lB = 0.f;

    // prologue: stage tile 0 into buffer 0
    gload_lds16(Kb + (size_t)krow * HDIM + c16s, KstW0);
    gload_lds16(Vbt + (size_t)krow * LSEQ + c16s, VstW0);
    __syncthreads();   // drains vmcnt: tile 0 visible

    for (int tt = 0; tt < nt; tt++) {
        int kv0 = tt << 6;
        int cur = tt & 1;
        // stage next tile into the other buffer (async; drains at barrier)
        if (tt + 1 < nt) {
            int kvn = kv0 + 64;
            gload_lds16(Kb + (size_t)(kvn + krow) * HDIM + c16s,
                        cur ? KstW0 : KstW1);
            gload_lds16(Vbt + (size_t)krow * LSEQ + kvn + c16s,
                        cur ? VstW0 : VstW1);
        }
        const unsigned short* Kc = &Kst[cur][0];
        const unsigned short* Vc = &Vst[cur][0];
        if (tt < ntaA)
            attn_tile(Kc, Vc, Pst, Pld, sw, kg, qc, kv0, q0A, qfA0, qfA1, ctxA, mA, lA);
        if (tt < ntaB)
            attn_tile(Kc, Vc, Pst, Pld, sw, kg, qc, kv0, q0B, qfB0, qfB1, ctxB, mB, lB);
        __syncthreads();   // drains staging vmcnt + separates buffers
    }
    // ---- normalize + store both states: lane holds q = q0+qc, d = df*16+kg*4+r ----
    float invA = 1.f / lA;
    unsigned short* CqA = Cb + (size_t)(q0A + qc) * E_DIM;
#pragma unroll
    for (int df = 0; df < 4; df++) {
        u16x4 o = { f2bf(ctxA[df][0] * invA), f2bf(ctxA[df][1] * invA),
                    f2bf(ctxA[df][2] * invA), f2bf(ctxA[df][3] * invA) };
        *(u16x4*)(CqA + df * 16 + kg * 4) = o;
    }
    float invB = 1.f / lB;
    unsigned short* CqB = Cb + (size_t)(q0B + qc) * E_DIM;
#pragma unroll
    for (int df = 0; df < 4; df++) {
        u16x4 o = { f2bf(ctxB[df][0] * invB), f2bf(ctxB[df][1] * invB),
                    f2bf(ctxB[df][2] * invB), f2bf(ctxB[df][3] * invB) };
        *(u16x4*)(CqB + df * 16 + kg * 4) = o;
    }
}

// ---------------- launcher ----------------
extern "C" void kernel_launch(void* const* d_in, const int* in_sizes, int n_in,
                              void* d_out, int out_size, void* d_ws, size_t ws_size,
                              hipStream_t stream)
{
    (void)in_sizes; (void)n_in; (void)out_size; (void)ws_size;
    const float* query = (const float*)d_in[0];
    const float* key_  = (const float*)d_in[1];
    const float* value = (const float*)d_in[2];
    const float* Wq = (const float*)d_in[5];
    const float* bq = (const float*)d_in[6];
    const float* Wk = (const float*)d_in[7];
    const float* bk = (const float*)d_in[8];
    const float* Wv = (const float*)d_in[9];
    const float* bv = (const float*)d_in[10];
    const float* Wo = (const float*)d_in[11];
    const float* bo = (const float*)d_in[12];
    float* out = (float*)d_out;

    char* ws = (char*)d_ws;
    const size_t MB = 1024 * 1024;
    unsigned short* Xq  = (unsigned short*)(ws + 0 * MB);
    unsigned short* Xk  = (unsigned short*)(ws + 8 * MB);
    unsigned short* Xv  = (unsigned short*)(ws + 16 * MB);
    unsigned short* Wqt = (unsigned short*)(ws + 24 * MB);
    unsigned short* Wkt = (unsigned short*)(ws + 26 * MB);
    unsigned short* Wvt = (unsigned short*)(ws + 28 * MB);
    unsigned short* Wot = (unsigned short*)(ws + 30 * MB);
    unsigned short* Qh  = (unsigned short*)(ws + 32 * MB);
    unsigned short* Kh  = (unsigned short*)(ws + 40 * MB);
    unsigned short* Vh  = (unsigned short*)(ws + 48 * MB);
    unsigned short* Vtp = (unsigned short*)(ws + 56 * MB);
    unsigned short* Ctx = (unsigned short*)(ws + 0 * MB);  // reuse Xq

    setup<<<dim3(2560), 256, 0, stream>>>(query, key_, value, Xq, Xk, Xv,
                                          Wq, Wk, Wv, Wo, Wqt, Wkt, Wvt, Wot);

    const float SCALE_Q = 0.18033688011112042f;  // log2(e) / sqrt(HD)=8
    gemm_qkv<<<dim3(32, 8, 3), 256, 0, stream>>>(Xq, Xk, Xv, Wqt, Wkt, Wvt,
                                                 bq, bk, bv, Qh, Kh, Vh, SCALE_Q);

    transpose_v<<<dim3(32, 32), 256, 0, stream>>>(Vh, Vtp);

    attn_causal<<<dim3(256), 512, 0, stream>>>(Qh, Kh, Vtp, Ctx);

    gemm_o<<<dim3(32, 16), 256, 0, stream>>>(Ctx, Wot, bo, out);
}

// Round 10
// 230.079 us; speedup vs baseline: 1.0604x; 1.0193x over previous
//
#include <hip/hip_runtime.h>

// Problem constants (fixed by the reference)
#define E_DIM 1024
#define NH    16
#define HDIM  64
#define BB    2
#define LSEQ  2048
#define MTOT  (BB*LSEQ)   // 4096 tokens

typedef float  f32x4  __attribute__((ext_vector_type(4)));
typedef __bf16 bf16x8 __attribute__((ext_vector_type(8)));
typedef unsigned int   u32x4 __attribute__((ext_vector_type(4)));
typedef unsigned short u16x4 __attribute__((ext_vector_type(4)));
typedef unsigned short u16x8 __attribute__((ext_vector_type(8)));

union U16 {           // 16-byte fragment: 8 bf16
    u32x4  u4;
    bf16x8 b;
};

__device__ inline unsigned short f2bf(float f) {
    union { __bf16 h; unsigned short u; } x;
    x.h = (__bf16)f;
    return x.u;
}

__device__ __forceinline__ float fexp2(float x) {
#if __has_builtin(__builtin_amdgcn_exp2f)
    return __builtin_amdgcn_exp2f(x);   // single v_exp_f32
#else
    return exp2f(x);
#endif
}

// async global->LDS, 16B per lane. LDS dest is wave-uniform base + lane*16.
__device__ __forceinline__ void gload_lds16(const unsigned short* g, unsigned short* l) {
    __builtin_amdgcn_global_load_lds(
        (const __attribute__((address_space(1))) void*)g,
        (__attribute__((address_space(3))) void*)l, 16, 0, 0);
}

// ---------------- setup: fp32->bf16 converts (3 tensors) + W transposes (4) ----------------
__global__ __launch_bounds__(256) void setup(
    const float* __restrict__ q, const float* __restrict__ k, const float* __restrict__ v,
    unsigned short* __restrict__ Xq, unsigned short* __restrict__ Xk,
    unsigned short* __restrict__ Xv,
    const float* __restrict__ Wq, const float* __restrict__ Wk,
    const float* __restrict__ Wv, const float* __restrict__ Wo,
    unsigned short* __restrict__ Wqt, unsigned short* __restrict__ Wkt,
    unsigned short* __restrict__ Wvt, unsigned short* __restrict__ Wot)
{
    __shared__ unsigned short tile[64][80];
    int bx = blockIdx.x;
    int t = threadIdx.x;
    if (bx < 1536) {
        int z = bx >> 9;             // 0..2
        int blk = bx & 511;
        const float* in = z == 0 ? q : (z == 1 ? k : v);
        unsigned short* out = z == 0 ? Xq : (z == 1 ? Xk : Xv);
        const int n = MTOT * E_DIM;
        int i = (blk * 256 + t) * 4;
        const int stride = 512 * 256 * 4;
        for (; i < n; i += stride) {
            f32x4 val = *(const f32x4*)(in + i);
            u16x4 o = { f2bf(val.x), f2bf(val.y), f2bf(val.z), f2bf(val.w) };
            *(u16x4*)(out + i) = o;
        }
    } else {
        int r = bx - 1536;
        int z = r >> 8;              // 0..3
        int g = r & 255;
        const float* W = z == 0 ? Wq : (z == 1 ? Wk : (z == 2 ? Wv : Wo));
        unsigned short* Wt = z == 0 ? Wqt : (z == 1 ? Wkt : (z == 2 ? Wvt : Wot));
        int n0 = (g & 15) * 64, k0 = (g >> 4) * 64;
#pragma unroll
        for (int i = 0; i < 4; i++) {
            int idx = i * 256 + t;
            int kr = idx >> 4, nc = (idx & 15) * 4;
            f32x4 val = *(const f32x4*)(W + (size_t)(k0 + kr) * E_DIM + n0 + nc);
            u16x4 o = { f2bf(val.x), f2bf(val.y), f2bf(val.z), f2bf(val.w) };
            *(u16x4*)&tile[kr][nc] = o;
        }
        __syncthreads();
#pragma unroll
        for (int i = 0; i < 2; i++) {
            int idx = i * 256 + t;
            int nr = idx >> 3, kc = (idx & 7) * 8;
            union { unsigned short s[8]; u16x8 v; } pack;
#pragma unroll
            for (int j = 0; j < 8; j++) pack.s[j] = tile[kc + j][nr];
            *(u16x8*)(Wt + (size_t)(n0 + nr) * E_DIM + k0 + kc) = pack.v;
        }
    }
}

// ---------------- batched QKV projection GEMM (z = 0,1,2) ----------------
// All outputs head-major [bh][L][64] bf16 (V transposed by separate kernel —
// fusing V^T into this epilogue measured +10us twice, R5/R6).
__global__ __launch_bounds__(256) void gemm_qkv(
    const unsigned short* __restrict__ Xq, const unsigned short* __restrict__ Xk,
    const unsigned short* __restrict__ Xv,
    const unsigned short* __restrict__ Wqt, const unsigned short* __restrict__ Wkt,
    const unsigned short* __restrict__ Wvt,
    const float* __restrict__ bqp, const float* __restrict__ bkp, const float* __restrict__ bvp,
    unsigned short* __restrict__ Qh, unsigned short* __restrict__ Kh,
    unsigned short* __restrict__ Vh, float scaleQ)
{
    int z = blockIdx.z;
    const unsigned short* A  = z == 0 ? Xq  : (z == 1 ? Xk  : Xv);
    const unsigned short* Bt = z == 0 ? Wqt : (z == 1 ? Wkt : Wvt);
    const float* bias        = z == 0 ? bqp : (z == 1 ? bkp : bvp);
    unsigned short* out      = z == 0 ? Qh  : (z == 1 ? Kh  : Vh);
    float scale              = z == 0 ? scaleQ : 1.0f;

    __shared__ unsigned short Al[128 * 64];
    __shared__ unsigned short Bl[128 * 64];
    int t = threadIdx.x;
    int lane = t & 63, w = t >> 6;
    int qc = lane & 15, kg = lane >> 4;
    int m0 = blockIdx.x * 128, n0 = blockIdx.y * 128;
    int wr = (w >> 1) * 64, wc = (w & 1) * 64;

    int srow = w * 32 + (lane >> 3);
    int scol = (lane & 7) * 8;
    const unsigned short* Ag = A + (size_t)(m0 + srow) * E_DIM + scol;
    const unsigned short* Bg = Bt + (size_t)(n0 + srow) * E_DIM + scol;
    unsigned short* Asl = &Al[(w * 32) * 64];
    unsigned short* Bsl = &Bl[(w * 32) * 64];

    f32x4 acc[4][4];
#pragma unroll
    for (int i = 0; i < 4; i++)
#pragma unroll
        for (int j = 0; j < 4; j++)
            acc[i][j] = {0.f, 0.f, 0.f, 0.f};

    for (int kt = 0; kt < E_DIM / 64; kt++) {
        const unsigned short* Ak = Ag + (kt << 6);
        const unsigned short* Bk = Bg + (kt << 6);
        __syncthreads();
#pragma unroll
        for (int i = 0; i < 4; i++) {
            gload_lds16(Ak + (size_t)i * 8 * E_DIM, Asl + i * 8 * 64);
            gload_lds16(Bk + (size_t)i * 8 * E_DIM, Bsl + i * 8 * 64);
        }
        __syncthreads();
#pragma unroll
        for (int k2 = 0; k2 < 2; k2++) {
            U16 af[4], bg[4];
#pragma unroll
            for (int mi = 0; mi < 4; mi++)
                af[mi].u4 = *(const u32x4*)&Al[(wr + mi * 16 + qc) * 64 + k2 * 32 + kg * 8];
#pragma unroll
            for (int ni = 0; ni < 4; ni++)
                bg[ni].u4 = *(const u32x4*)&Bl[(wc + ni * 16 + qc) * 64 + k2 * 32 + kg * 8];
#pragma unroll
            for (int mi = 0; mi < 4; mi++)
#pragma unroll
                for (int ni = 0; ni < 4; ni++)
                    acc[mi][ni] = __builtin_amdgcn_mfma_f32_16x16x32_bf16(
                        af[mi].b, bg[ni].b, acc[mi][ni], 0, 0, 0);
        }
    }
#pragma unroll
    for (int ni = 0; ni < 4; ni++) {
        int n = n0 + wc + ni * 16 + qc;
        float bval = bias[n];
        int h = n >> 6, hd = n & 63;
#pragma unroll
        for (int mi = 0; mi < 4; mi++) {
#pragma unroll
            for (int r = 0; r < 4; r++) {
                int m = m0 + wr + mi * 16 + kg * 4 + r;
                float v = (acc[mi][ni][r] + bval) * scale;
                int b = m >> 11, l = m & (LSEQ - 1);
                out[(((size_t)(b * NH + h)) * LSEQ + l) * HDIM + hd] = f2bf(v);
            }
        }
    }
}

// ---------------- V [bh][L][64] -> Vt [bh][64][L] (bf16) ----------------
__global__ __launch_bounds__(256) void transpose_v(
    const unsigned short* __restrict__ V, unsigned short* __restrict__ Vt)
{
    __shared__ unsigned short tile[64][80];
    int l0 = blockIdx.x * 64;
    int bh = blockIdx.y;
    const unsigned short* Vb = V + (size_t)bh * LSEQ * HDIM;
    unsigned short* Vtb = Vt + (size_t)bh * HDIM * LSEQ;
    int t = threadIdx.x;
#pragma unroll
    for (int i = 0; i < 2; i++) {
        int idx = i * 256 + t;
        int lr = idx >> 3, dc = (idx & 7) * 8;
        *(u16x8*)&tile[lr][dc] = *(const u16x8*)(Vb + (size_t)(l0 + lr) * HDIM + dc);
    }
    __syncthreads();
#pragma unroll
    for (int i = 0; i < 2; i++) {
        int idx = i * 256 + t;
        int dr = idx >> 3, lc = (idx & 7) * 8;
        union { unsigned short s[8]; u16x8 v; } pack;
#pragma unroll
        for (int j = 0; j < 8; j++) pack.s[j] = tile[lc + j][dr];
        *(u16x8*)(Vtb + (size_t)dr * LSEQ + l0 + lc) = pack.v;
    }
}

// ---------------- O-projection GEMM: 128x64 tile ----------------
__global__ __launch_bounds__(256) void gemm_o(
    const unsigned short* __restrict__ A, const unsigned short* __restrict__ Bt,
    const float* __restrict__ bias, float* __restrict__ outF)
{
    __shared__ unsigned short Al[128 * 64];
    __shared__ unsigned short Bl[64 * 64];
    int t = threadIdx.x;
    int lane = t & 63, w = t >> 6;
    int qc = lane & 15, kg = lane >> 4;
    int m0 = blockIdx.x * 128, n0 = blockIdx.y * 64;
    int wr = (w >> 1) * 64, wc = (w & 1) * 32;

    int srA = w * 32 + (lane >> 3);
    int srB = w * 16 + (lane >> 3);
    int scol = (lane & 7) * 8;
    const unsigned short* Ag = A + (size_t)(m0 + srA) * E_DIM + scol;
    const unsigned short* Bg = Bt + (size_t)(n0 + srB) * E_DIM + scol;
    unsigned short* Asl = &Al[(w * 32) * 64];
    unsigned short* Bsl = &Bl[(w * 16) * 64];

    f32x4 acc[4][2];
#pragma unroll
    for (int i = 0; i < 4; i++)
#pragma unroll
        for (int j = 0; j < 2; j++)
            acc[i][j] = {0.f, 0.f, 0.f, 0.f};

    for (int kt = 0; kt < E_DIM / 64; kt++) {
        const unsigned short* Ak = Ag + (kt << 6);
        const unsigned short* Bk = Bg + (kt << 6);
        __syncthreads();
#pragma unroll
        for (int i = 0; i < 4; i++)
            gload_lds16(Ak + (size_t)i * 8 * E_DIM, Asl + i * 8 * 64);
#pragma unroll
        for (int i = 0; i < 2; i++)
            gload_lds16(Bk + (size_t)i * 8 * E_DIM, Bsl + i * 8 * 64);
        __syncthreads();
#pragma unroll
        for (int k2 = 0; k2 < 2; k2++) {
            U16 af[4], bg[2];
#pragma unroll
            for (int mi = 0; mi < 4; mi++)
                af[mi].u4 = *(const u32x4*)&Al[(wr + mi * 16 + qc) * 64 + k2 * 32 + kg * 8];
#pragma unroll
            for (int ni = 0; ni < 2; ni++)
                bg[ni].u4 = *(const u32x4*)&Bl[(wc + ni * 16 + qc) * 64 + k2 * 32 + kg * 8];
#pragma unroll
            for (int mi = 0; mi < 4; mi++)
#pragma unroll
                for (int ni = 0; ni < 2; ni++)
                    acc[mi][ni] = __builtin_amdgcn_mfma_f32_16x16x32_bf16(
                        af[mi].b, bg[ni].b, acc[mi][ni], 0, 0, 0);
        }
    }
#pragma unroll
    for (int ni = 0; ni < 2; ni++) {
        int n = n0 + wc + ni * 16 + qc;
        float bval = bias[n];
#pragma unroll
        for (int mi = 0; mi < 4; mi++) {
#pragma unroll
            for (int r = 0; r < 4; r++) {
                int m = m0 + wr + mi * 16 + kg * 4 + r;
                outF[(size_t)m * E_DIM + n] = acc[mi][ni][r] + bval;
            }
        }
    }
}

// ---- per-128-wide-tile attention compute for one q-state ----
// Kc: [128 kv][64 d] swizzled; Vc: [64 d][128 kv] swizzled.
__device__ __forceinline__ void attn_tile(
    const unsigned short* __restrict__ Kc, const unsigned short* __restrict__ Vc,
    unsigned short* __restrict__ Pst, const unsigned short* __restrict__ Pld,
    int sw, int kg, int qc, int kv0, int q0w,
    const U16& qf0, const U16& qf1,
    f32x4 ctx[4], float& mrun, float& lrun)
{
    // ---- S^T = K Q^T : rows kv = f*16+kg*4+r (f 0..7), col q = qc ----
    f32x4 s[8];
    __builtin_amdgcn_s_setprio(1);
#pragma unroll
    for (int f = 0; f < 8; f++) {
        U16 k0_, k1_;   // A-frag row kv=f*16+qc, k=d (2 halves)
        k0_.u4 = *(const u32x4*)&Kc[(f * 16 + qc) * 64 + ((kg * 8) ^ sw)];
        k1_.u4 = *(const u32x4*)&Kc[(f * 16 + qc) * 64 + ((32 + kg * 8) ^ sw)];
        f32x4 z = {0.f, 0.f, 0.f, 0.f};
        z = __builtin_amdgcn_mfma_f32_16x16x32_bf16(k0_.b, qf0.b, z, 0, 0, 0);
        z = __builtin_amdgcn_mfma_f32_16x16x32_bf16(k1_.b, qf1.b, z, 0, 0, 0);
        s[f] = z;
    }
    __builtin_amdgcn_s_setprio(0);
    // ---- causal mask (diagonal tiles only) ----
    if (kv0 + 127 > q0w) {
        int qi = q0w + qc;
#pragma unroll
        for (int f = 0; f < 8; f++) {
#pragma unroll
            for (int r = 0; r < 4; r++) {
                if (kv0 + f * 16 + kg * 4 + r > qi) s[f][r] = -1e30f;
            }
        }
    }
    // ---- per-lane softmax (32 regs) + 2 cross-lane steps ----
    float mf[8];
#pragma unroll
    for (int f = 0; f < 8; f++)
        mf[f] = fmaxf(fmaxf(s[f][0], s[f][1]), fmaxf(s[f][2], s[f][3]));
    float tm = fmaxf(fmaxf(fmaxf(mf[0], mf[1]), fmaxf(mf[2], mf[3])),
                     fmaxf(fmaxf(mf[4], mf[5]), fmaxf(mf[6], mf[7])));
    tm = fmaxf(tm, __shfl_xor(tm, 16));
    tm = fmaxf(tm, __shfl_xor(tm, 32));
    float mn;
    if (__all(tm - mrun <= 8.0f)) {       // T13 defer-max
        mn = mrun;
    } else {
        mn = fmaxf(mrun, tm);
        float sc = fexp2(mrun - mn);
        mrun = mn;
        lrun *= sc;
#pragma unroll
        for (int df = 0; df < 4; df++) ctx[df] *= sc;
    }
#pragma unroll
    for (int f = 0; f < 8; f++)
#pragma unroll
        for (int r = 0; r < 4; r++)
            s[f][r] = fexp2(s[f][r] - mn);
    float rs = 0.f;
#pragma unroll
    for (int f = 0; f < 8; f++)
        rs += (s[f][0] + s[f][1]) + (s[f][2] + s[f][3]);
    rs += __shfl_xor(rs, 16);
    rs += __shfl_xor(rs, 32);
    lrun += rs;
    // ---- store P[q=qc][kv], 8x 8B chunks ----
#pragma unroll
    for (int f = 0; f < 8; f++) {
        u16x4 p = { f2bf(s[f][0]), f2bf(s[f][1]), f2bf(s[f][2]), f2bf(s[f][3]) };
        *(u16x4*)(Pst + f * 16) = p;
    }
    // ---- ctx^T += V^T P^T : k2 now 0..3 (128 kv) ----
    __builtin_amdgcn_s_setprio(1);
#pragma unroll
    for (int k2 = 0; k2 < 4; k2++) {
        U16 ap;
        ap.u4 = *(const u32x4*)(Pld + k2 * 32);
#pragma unroll
        for (int df = 0; df < 4; df++) {
            U16 vf;   // A-frag row d=df*16+qc, k=kv (quarter k2)
            vf.u4 = *(const u32x4*)&Vc[(df * 16 + qc) * 128 +
                                       ((k2 * 32 + kg * 8) ^ sw)];
            ctx[df] = __builtin_amdgcn_mfma_f32_16x16x32_bf16(
                vf.b, ap.b, ctx[df], 0, 0, 0);
        }
    }
    __builtin_amdgcn_s_setprio(0);
}

// ---------------- causal flash attention: dual-q-tile, KVBLK=128 ----------------
// Qh/Kh: [bh][L][64] bf16 (Q pre-scaled by log2e/8). Vt: [bh][64][L] bf16.
// Grid 256 linear, 512 threads (8 waves). Block owns bh; processes q-blocks
// qbA = pr and qbB = 15-pr simultaneously against one staged K/V stream.
// KVBLK=128: halves barrier-iteration count vs R8 (32 -> 16 max) at identical
// total staged bytes/compute — attacks the measured ~3300 cyc/iter fixed cost.
__global__ __launch_bounds__(512, 2) void attn_causal(
    const unsigned short* __restrict__ Qh, const unsigned short* __restrict__ Kh,
    const unsigned short* __restrict__ Vt, unsigned short* __restrict__ Ctx)
{
    __shared__ unsigned short Kst[2][128 * 64];   // [kv][d], swizzled, 16KB/buf
    __shared__ unsigned short Vst[2][64 * 128];   // [d][kv], swizzled, 16KB/buf
    __shared__ unsigned short Pl[8][16 * 136];    // per-wave P[q][kv], stride 136

    // XCD chunking: XCD x gets flat in [32x,32x+32) -> bh in [4x,4x+4): K/V fit L2
    int flat_hw = blockIdx.x;
    int flat = (flat_hw & 7) * 32 + (flat_hw >> 3);
    int bh = flat >> 3;          // 0..31
    int pr = flat & 7;           // qbA = pr, qbB = 15-pr

    int t = threadIdx.x;
    int w = t >> 6, lane = t & 63;
    int qc = lane & 15, kg = lane >> 4;

    const unsigned short* Qb  = Qh + (size_t)bh * LSEQ * HDIM;
    const unsigned short* Kb  = Kh + (size_t)bh * LSEQ * HDIM;
    const unsigned short* Vbt = Vt + (size_t)bh * HDIM * LSEQ;
    int b = bh >> 4, h = bh & 15;
    unsigned short* Cb = Ctx + ((size_t)b * LSEQ) * E_DIM + h * HDIM;

    // K staging: wave w stages kv rows [16w,16w+16), 2 instrs of 8 rows.
    // lane -> row 16w+8i+(lane>>3), col16 lane&7; source col pre-swizzled.
    int ksrow = lane >> 3;                       // 0..7 within 8-row chunk
    int kscol = ((lane & 7) ^ ksrow) * 8;        // row&7 == lane>>3 (chunks 8-aligned)
    // V staging: wave w stages d rows [8w,8w+8), 2 instrs of 4 rows.
    // lane -> row 8w+4i+(lane>>4), col16 lane&15; source col pre-swizzled by d&7.
    int vsrow = lane >> 4;                       // 0..3 within 4-row chunk
    int vscol0 = ((lane & 15) ^ (0 + vsrow)) * 8;    // i=0: d&7 = vsrow
    int vscol1 = ((lane & 15) ^ (4 + vsrow)) * 8;    // i=1: d&7 = 4+vsrow
    unsigned short* KstW0 = &Kst[0][(16 * w) * 64];
    unsigned short* KstW1 = &Kst[1][(16 * w) * 64];
    unsigned short* VstW0 = &Vst[0][(8 * w) * 128];
    unsigned short* VstW1 = &Vst[1][(8 * w) * 128];
    const unsigned short* KgA = Kb + (size_t)(16 * w + ksrow) * HDIM + kscol;      // +8 rows for i=1
    const unsigned short* VgA = Vbt + (size_t)(8 * w + vsrow) * LSEQ;              // cols added per-instr

    unsigned short* Pw = &Pl[w][0];
    unsigned short* Pst = Pw + qc * 136 + kg * 4;        // store: row q=qc, col f*16+kg*4
    const unsigned short* Pld = Pw + qc * 136 + kg * 8;  // load B-frag: col q=qc, k=kv

    int sw = (qc & 7) * 8;   // read-side swizzle term

    int q0A = pr * 128 + w * 16;
    int q0B = (15 - pr) * 128 + w * 16;
    int nt   = 16 - pr;                    // staging iterations (uniform per block)
    int ntaA = (q0A + 143) >> 7;           // active tiles, state A
    int ntaB = (q0B + 143) >> 7;           // active tiles, state B (= heavy)

    // Q B-frags (col=q=lane&15, k=d=kg*8+j) for both states
    U16 qfA0, qfA1, qfB0, qfB1;
    qfA0.u4 = *(const u32x4*)(Qb + (size_t)(q0A + qc) * HDIM + kg * 8);
    qfA1.u4 = *(const u32x4*)(Qb + (size_t)(q0A + qc) * HDIM + 32 + kg * 8);
    qfB0.u4 = *(const u32x4*)(Qb + (size_t)(q0B + qc) * HDIM + kg * 8);
    qfB1.u4 = *(const u32x4*)(Qb + (size_t)(q0B + qc) * HDIM + 32 + kg * 8);

    f32x4 ctxA[4], ctxB[4];
#pragma unroll
    for (int df = 0; df < 4; df++) {
        ctxA[df] = {0.f, 0.f, 0.f, 0.f};
        ctxB[df] = {0.f, 0.f, 0.f, 0.f};
    }
    float mA = -1e30f, lA = 0.f, mB = -1e30f, lB = 0.f;

    // prologue: stage tile 0 into buffer 0 (4 gloads: 2 K chunks + 2 V chunks)
    gload_lds16(KgA, KstW0);
    gload_lds16(KgA + (size_t)8 * HDIM, KstW0 + 8 * 64);
    gload_lds16(VgA + vscol0, VstW0);
    gload_lds16(VgA + (size_t)4 * LSEQ + vscol1, VstW0 + 4 * 128);
    __syncthreads();   // drains vmcnt: tile 0 visible

    for (int tt = 0; tt < nt; tt++) {
        int kv0 = tt << 7;
        int cur = tt & 1;
        // stage next 128-tile into the other buffer (async; drains at barrier)
        if (tt + 1 < nt) {
            int kvn = kv0 + 128;
            unsigned short* Kd = cur ? KstW0 : KstW1;
            unsigned short* Vd = cur ? VstW0 : VstW1;
            gload_lds16(KgA + (size_t)kvn * HDIM, Kd);
            gload_lds16(KgA + (size_t)(kvn + 8) * HDIM, Kd + 8 * 64);
            gload_lds16(VgA + kvn + vscol0, Vd);
            gload_lds16(VgA + (size_t)4 * LSEQ + kvn + vscol1, Vd + 4 * 128);
        }
        const unsigned short* Kc = &Kst[cur][0];
        const unsigned short* Vc = &Vst[cur][0];
        if (tt < ntaA)
            attn_tile(Kc, Vc, Pst, Pld, sw, kg, qc, kv0, q0A, qfA0, qfA1, ctxA, mA, lA);
        if (tt < ntaB)
            attn_tile(Kc, Vc, Pst, Pld, sw, kg, qc, kv0, q0B, qfB0, qfB1, ctxB, mB, lB);
        __syncthreads();   // drains staging vmcnt + separates buffers
    }
    // ---- normalize + store both states: lane holds q = q0+qc, d = df*16+kg*4+r ----
    float invA = 1.f / lA;
    unsigned short* CqA = Cb + (size_t)(q0A + qc) * E_DIM;
#pragma unroll
    for (int df = 0; df < 4; df++) {
        u16x4 o = { f2bf(ctxA[df][0] * invA), f2bf(ctxA[df][1] * invA),
                    f2bf(ctxA[df][2] * invA), f2bf(ctxA[df][3] * invA) };
        *(u16x4*)(CqA + df * 16 + kg * 4) = o;
    }
    float invB = 1.f / lB;
    unsigned short* CqB = Cb + (size_t)(q0B + qc) * E_DIM;
#pragma unroll
    for (int df = 0; df < 4; df++) {
        u16x4 o = { f2bf(ctxB[df][0] * invB), f2bf(ctxB[df][1] * invB),
                    f2bf(ctxB[df][2] * invB), f2bf(ctxB[df][3] * invB) };
        *(u16x4*)(CqB + df * 16 + kg * 4) = o;
    }
}

// ---------------- launcher ----------------
extern "C" void kernel_launch(void* const* d_in, const int* in_sizes, int n_in,
                              void* d_out, int out_size, void* d_ws, size_t ws_size,
                              hipStream_t stream)
{
    (void)in_sizes; (void)n_in; (void)out_size; (void)ws_size;
    const float* query = (const float*)d_in[0];
    const float* key_  = (const float*)d_in[1];
    const float* value = (const float*)d_in[2];
    const float* Wq = (const float*)d_in[5];
    const float* bq = (const float*)d_in[6];
    const float* Wk = (const float*)d_in[7];
    const float* bk = (const float*)d_in[8];
    const float* Wv = (const float*)d_in[9];
    const float* bv = (const float*)d_in[10];
    const float* Wo = (const float*)d_in[11];
    const float* bo = (const float*)d_in[12];
    float* out = (float*)d_out;

    char* ws = (char*)d_ws;
    const size_t MB = 1024 * 1024;
    unsigned short* Xq  = (unsigned short*)(ws + 0 * MB);
    unsigned short* Xk  = (unsigned short*)(ws + 8 * MB);
    unsigned short* Xv  = (unsigned short*)(ws + 16 * MB);
    unsigned short* Wqt = (unsigned short*)(ws + 24 * MB);
    unsigned short* Wkt = (unsigned short*)(ws + 26 * MB);
    unsigned short* Wvt = (unsigned short*)(ws + 28 * MB);
    unsigned short* Wot = (unsigned short*)(ws + 30 * MB);
    unsigned short* Qh  = (unsigned short*)(ws + 32 * MB);
    unsigned short* Kh  = (unsigned short*)(ws + 40 * MB);
    unsigned short* Vh  = (unsigned short*)(ws + 48 * MB);
    unsigned short* Vtp = (unsigned short*)(ws + 56 * MB);
    unsigned short* Ctx = (unsigned short*)(ws + 0 * MB);  // reuse Xq

    setup<<<dim3(2560), 256, 0, stream>>>(query, key_, value, Xq, Xk, Xv,
                                          Wq, Wk, Wv, Wo, Wqt, Wkt, Wvt, Wot);

    const float SCALE_Q = 0.18033688011112042f;  // log2(e) / sqrt(HD)=8
    gemm_qkv<<<dim3(32, 8, 3), 256, 0, stream>>>(Xq, Xk, Xv, Wqt, Wkt, Wvt,
                                                 bq, bk, bv, Qh, Kh, Vh, SCALE_Q);

    transpose_v<<<dim3(32, 32), 256, 0, stream>>>(Vh, Vtp);

    attn_causal<<<dim3(256), 512, 0, stream>>>(Qh, Kh, Vtp, Ctx);

    gemm_o<<<dim3(32, 16), 256, 0, stream>>>(Ctx, Wot, bo, out);
}